// Round 1
// baseline (4206.772 us; speedup 1.0000x reference)
//
#include <hip/hip_runtime.h>
#include <math.h>

#define THREADS 512

// LDS layout (floats):
//   S  : [8][64][4]   = 2048   sampled features, k-vectorized transposed
//   Ab : [64][64][4]  = 16384  activations ping
//   Bb : [64][64][4]  = 16384  activations pong
// total = 34816 floats = 139264 bytes (dynamic LDS, > 64KB default)

__device__ __forceinline__ float fast_sigmoid(float x) {
    return 1.0f / (1.0f + __expf(-x));
}

__device__ __forceinline__ float samp_ch(const float* __restrict__ vc,
                                         int i000, int i001, int i010, int i011,
                                         int i100, int i101, int i110, int i111,
                                         float w000, float w001, float w010, float w011,
                                         float w100, float w101, float w110, float w111) {
    return vc[i000] * w000 + vc[i001] * w001 + vc[i010] * w010 + vc[i011] * w011 +
           vc[i100] * w100 + vc[i101] * w101 + vc[i110] * w110 + vc[i111] * w111;
}

// One dense layer + sin: out[j] = sin(b[j] + sum_k in[k] * W[j][k])
// in/out are LDS in [k/4][64 pts][4] layout. Each thread: point p, 32 neurons
// starting at g*32, processed in 4 chunks of 8 accumulators.
template <int K>
__device__ __forceinline__ void dense_sin_layer(const float* __restrict__ inb,
                                                float* __restrict__ outb,
                                                const float* __restrict__ W,
                                                const float* __restrict__ bias,
                                                int p, int g) {
#pragma unroll
    for (int chunk = 0; chunk < 4; ++chunk) {
        // wave-uniform neuron base -> scalar loads for W rows
        const int j0 = __builtin_amdgcn_readfirstlane(g * 32 + chunk * 8);
        float acc[8];
#pragma unroll
        for (int jj = 0; jj < 8; ++jj) acc[jj] = bias[j0 + jj];
#pragma unroll 4
        for (int k4 = 0; k4 < K / 4; ++k4) {
            const float4 a = *(const float4*)(inb + k4 * 256 + p * 4);
#pragma unroll
            for (int jj = 0; jj < 8; ++jj) {
                const float4 w = *(const float4*)(W + (size_t)(j0 + jj) * K + k4 * 4);
                acc[jj] += a.x * w.x;
                acc[jj] += a.y * w.y;
                acc[jj] += a.z * w.z;
                acc[jj] += a.w * w.w;
            }
        }
        float4 o;
        o.x = __sinf(acc[0]); o.y = __sinf(acc[1]);
        o.z = __sinf(acc[2]); o.w = __sinf(acc[3]);
        *(float4*)(outb + ((j0 >> 2) + 0) * 256 + p * 4) = o;
        o.x = __sinf(acc[4]); o.y = __sinf(acc[5]);
        o.z = __sinf(acc[6]); o.w = __sinf(acc[7]);
        *(float4*)(outb + ((j0 >> 2) + 1) * 256 + p * 4) = o;
    }
}

extern __shared__ float lds[];

__global__ __launch_bounds__(THREADS)
void siren_fused(const float* __restrict__ points,
                 const float* __restrict__ vol,
                 const float* __restrict__ W0, const float* __restrict__ b0,
                 const float* __restrict__ W1, const float* __restrict__ b1,
                 const float* __restrict__ W2, const float* __restrict__ b2,
                 const float* __restrict__ W3, const float* __restrict__ b3,
                 const float* __restrict__ Wf, const float* __restrict__ bfin,
                 float* __restrict__ out,
                 long long total, int N) {
    float* S  = lds;
    float* Ab = lds + 2048;
    float* Bb = lds + 2048 + 16384;

    const int tid = (int)threadIdx.x;
    const int p = tid & 63;   // point within tile
    const int g = tid >> 6;   // neuron / channel group (0..7)

    const long long gidx = (long long)blockIdx.x * 64 + p;
    const long long gp = gidx < total ? gidx : total - 1;
    const int bi = (int)(gp / N);

    // ---------------- trilinear border sample (align_corners=False) ----------
    const float* pp = points + gp * 3;
    const float sc = 1.0f / 0.6f;  // grid = p / (VOXEL_LENGTH/2)
    const float ix = (pp[0] * sc + 1.0f) * 16.0f - 0.5f;  // ((g+1)*32-1)*0.5
    const float iy = (pp[1] * sc + 1.0f) * 16.0f - 0.5f;
    const float iz = (pp[2] * sc + 1.0f) * 16.0f - 0.5f;
    const float fx = floorf(ix), fy = floorf(iy), fz = floorf(iz);
    const float wx = ix - fx, wy = iy - fy, wz = iz - fz;
    const int x0 = (int)fminf(fmaxf(fx, 0.0f), 31.0f);
    const int x1 = (int)fminf(fmaxf(fx + 1.0f, 0.0f), 31.0f);
    const int y0 = (int)fminf(fmaxf(fy, 0.0f), 31.0f);
    const int y1 = (int)fminf(fmaxf(fy + 1.0f, 0.0f), 31.0f);
    const int z0 = (int)fminf(fmaxf(fz, 0.0f), 31.0f);
    const int z1 = (int)fminf(fmaxf(fz + 1.0f, 0.0f), 31.0f);
    const int i000 = (z0 * 32 + y0) * 32 + x0;
    const int i001 = (z0 * 32 + y0) * 32 + x1;
    const int i010 = (z0 * 32 + y1) * 32 + x0;
    const int i011 = (z0 * 32 + y1) * 32 + x1;
    const int i100 = (z1 * 32 + y0) * 32 + x0;
    const int i101 = (z1 * 32 + y0) * 32 + x1;
    const int i110 = (z1 * 32 + y1) * 32 + x0;
    const int i111 = (z1 * 32 + y1) * 32 + x1;
    const float omx = 1.0f - wx, omy = 1.0f - wy, omz = 1.0f - wz;
    const float w000 = omz * omy * omx, w001 = omz * omy * wx;
    const float w010 = omz * wy * omx,  w011 = omz * wy * wx;
    const float w100 = wz * omy * omx,  w101 = wz * omy * wx;
    const float w110 = wz * wy * omx,   w111 = wz * wy * wx;

    // each thread samples 4 channels: c = g*4 .. g*4+3
    const float* vb = vol + ((size_t)bi * 32 + (size_t)g * 4) * 32768;
    float4 sv;
    sv.x = samp_ch(vb + 0 * 32768, i000, i001, i010, i011, i100, i101, i110, i111,
                   w000, w001, w010, w011, w100, w101, w110, w111);
    sv.y = samp_ch(vb + 1 * 32768, i000, i001, i010, i011, i100, i101, i110, i111,
                   w000, w001, w010, w011, w100, w101, w110, w111);
    sv.z = samp_ch(vb + 2 * 32768, i000, i001, i010, i011, i100, i101, i110, i111,
                   w000, w001, w010, w011, w100, w101, w110, w111);
    sv.w = samp_ch(vb + 3 * 32768, i000, i001, i010, i011, i100, i101, i110, i111,
                   w000, w001, w010, w011, w100, w101, w110, w111);
    *(float4*)(S + g * 256 + p * 4) = sv;
    __syncthreads();

    // ---------------- MLP ----------------
    dense_sin_layer<32>(S, Ab, W0, b0, p, g);
    __syncthreads();
    dense_sin_layer<256>(Ab, Bb, W1, b1, p, g);
    __syncthreads();
    dense_sin_layer<256>(Bb, Ab, W2, b2, p, g);
    __syncthreads();
    dense_sin_layer<256>(Ab, Bb, W3, b3, p, g);
    __syncthreads();

    // ---------------- final 256 -> 4, sigmoid on rgb ----------------
    if (g < 4 && gidx < total) {
        float acc = bfin[g];
        const float* Wr = Wf + (size_t)g * 256;
#pragma unroll 4
        for (int k4 = 0; k4 < 64; ++k4) {
            const float4 a = *(const float4*)(Bb + k4 * 256 + p * 4);
            const float4 w = *(const float4*)(Wr + k4 * 4);
            acc += a.x * w.x + a.y * w.y + a.z * w.z + a.w * w.w;
        }
        const float val = (g < 3) ? fast_sigmoid(acc) : acc;
        out[gidx * 4 + g] = val;
    }
}

extern "C" void kernel_launch(void* const* d_in, const int* in_sizes, int n_in,
                              void* d_out, int out_size, void* d_ws, size_t ws_size,
                              hipStream_t stream) {
    const float* points = (const float*)d_in[0];
    const float* vol    = (const float*)d_in[1];
    const float* W0 = (const float*)d_in[2];
    const float* b0 = (const float*)d_in[3];
    const float* W1 = (const float*)d_in[4];
    const float* b1 = (const float*)d_in[5];
    const float* W2 = (const float*)d_in[6];
    const float* b2 = (const float*)d_in[7];
    const float* W3 = (const float*)d_in[8];
    const float* b3 = (const float*)d_in[9];
    const float* Wf = (const float*)d_in[10];
    const float* bf = (const float*)d_in[11];

    const int B = in_sizes[1] / (32 * 32 * 32 * 32);   // feature_volume = B*32*32^3
    const int N = in_sizes[0] / (3 * B);               // points = B*N*3
    const long long total = (long long)B * N;
    const int tiles = (int)((total + 63) / 64);

    const size_t shmem = (size_t)(2048 + 2 * 16384) * sizeof(float);  // 139264 B
    hipFuncSetAttribute((const void*)siren_fused,
                        hipFuncAttributeMaxDynamicSharedMemorySize, (int)shmem);

    siren_fused<<<tiles, THREADS, shmem, stream>>>(
        points, vol, W0, b0, W1, b1, W2, b2, W3, b3, Wf, bf,
        (float*)d_out, total, N);
}

// Round 2
// 208.176 us; speedup vs baseline: 20.2078x; 20.2078x over previous
//
#include <hip/hip_runtime.h>
#include <math.h>

#define THREADS 512

typedef __attribute__((ext_vector_type(8))) short bf16x8;
typedef __attribute__((ext_vector_type(4))) float f32x4;

// ws layout (bf16 elem offsets for weights; then f32 channel-last volume)
#define W0_OFF 0        // 256*32
#define W1_OFF 8192     // 256*256
#define W2_OFF 73728
#define W3_OFF 139264
#define WF_OFF 204800   // 4*256
#define WTS_BYTES 411648            // 205824 * 2, 16B-aligned
#define VOL_BYTES (2u*32768u*32u*4u)
#define WS_NEED (WTS_BYTES + VOL_BYTES)

__device__ __forceinline__ ushort f2bf(float f) {
    union { float f; unsigned u; } v; v.f = f;
    unsigned r = v.u + 0x7FFFu + ((v.u >> 16) & 1u);
    return (ushort)(r >> 16);
}

__device__ __forceinline__ float fast_sigmoid(float x) {
    return 1.0f / (1.0f + __expf(-x));
}

// ---------------- prep kernels ----------------
__global__ void cvt_bf16(const float* __restrict__ src, ushort* __restrict__ dst, int n) {
    int i = blockIdx.x * 256 + threadIdx.x;
    if (i < n) dst[i] = f2bf(src[i]);
}

// vol [B][32][32768] f32 -> dst [B*32768][32] f32 (channel-last)
__global__ void vol_chlast(const float* __restrict__ vol, float* __restrict__ dst, int nvox) {
    int v = blockIdx.x * 256 + threadIdx.x;
    if (v >= nvox) return;
    const int b = v >> 15, idx = v & 32767;
    const float* s = vol + (size_t)b * 32 * 32768 + idx;
    float* d = dst + (size_t)v * 32;
#pragma unroll
    for (int c = 0; c < 32; ++c) d[c] = s[(size_t)c * 32768];
}

// ---------------- main fused kernel ----------------
// LDS (ushort): S[64][40]=2560, A0[64][264]=16896, A1[64][264]=16896 -> 72704 B
extern __shared__ ushort ldsu[];

template <int K, int RS>
__device__ __forceinline__ void dense_sin_layer(const ushort* __restrict__ in,
                                                ushort* __restrict__ outb,
                                                const ushort* __restrict__ Wl,
                                                const float* __restrict__ bias,
                                                int w, int lr, int lc) {
    f32x4 acc[4][2];
    const f32x4 bv0 = *(const f32x4*)(bias + w * 32 + lc * 4);
    const f32x4 bv1 = *(const f32x4*)(bias + w * 32 + 16 + lc * 4);
#pragma unroll
    for (int pt = 0; pt < 4; ++pt) { acc[pt][0] = bv0; acc[pt][1] = bv1; }

#pragma unroll
    for (int ks = 0; ks < K / 32; ++ks) {
        const int kb = ks * 32 + lc * 8;
        const bf16x8 wf0 = *(const bf16x8*)(Wl + (size_t)(w * 32 + lr) * K + kb);
        const bf16x8 wf1 = *(const bf16x8*)(Wl + (size_t)(w * 32 + 16 + lr) * K + kb);
#pragma unroll
        for (int pt = 0; pt < 4; ++pt) {
            const bf16x8 af = *(const bf16x8*)(in + (pt * 16 + lr) * RS + kb);
            acc[pt][0] = __builtin_amdgcn_mfma_f32_16x16x32_bf16(wf0, af, acc[pt][0], 0, 0, 0);
            acc[pt][1] = __builtin_amdgcn_mfma_f32_16x16x32_bf16(wf1, af, acc[pt][1], 0, 0, 0);
        }
    }
    // epilogue: sin -> bf16, rows are 4 consecutive neurons per lane -> b64 write
#pragma unroll
    for (int pt = 0; pt < 4; ++pt) {
#pragma unroll
        for (int nt = 0; nt < 2; ++nt) {
            ushort4 o;
            o.x = f2bf(__sinf(acc[pt][nt][0]));
            o.y = f2bf(__sinf(acc[pt][nt][1]));
            o.z = f2bf(__sinf(acc[pt][nt][2]));
            o.w = f2bf(__sinf(acc[pt][nt][3]));
            *(ushort4*)(outb + (pt * 16 + lr) * 264 + (w * 32 + nt * 16 + lc * 4)) = o;
        }
    }
}

__global__ __launch_bounds__(THREADS, 4)
void siren_mfma(const float* __restrict__ points,
                const float* __restrict__ vol,
                const float* __restrict__ b0, const float* __restrict__ b1,
                const float* __restrict__ b2, const float* __restrict__ b3,
                const float* __restrict__ bfin,
                const ushort* __restrict__ Wb,
                const float* __restrict__ volcl, int use_cl,
                float* __restrict__ out, long long total, int N) {
    ushort* S  = ldsu;            // [64][40]
    ushort* A0 = ldsu + 2560;     // [64][264]
    ushort* A1 = A0 + 16896;

    const int tid = (int)threadIdx.x;
    const int p = tid & 63;       // point (== lane)
    const int g = tid >> 6;       // wave id
    const int lr = tid & 15;
    const int lc = (tid >> 4) & 3;

    const long long base = (long long)blockIdx.x * 64;
    const long long gidx = base + p;
    const long long gp = gidx < total ? gidx : total - 1;
    const int bi = (int)(gp / N);

    // ---- trilinear border sample: thread (p, g) -> channels g*4..g*4+3 ----
    {
        const float* pp = points + gp * 3;
        const float sc = 1.0f / 0.6f;
        const float ix = (pp[0] * sc + 1.0f) * 16.0f - 0.5f;
        const float iy = (pp[1] * sc + 1.0f) * 16.0f - 0.5f;
        const float iz = (pp[2] * sc + 1.0f) * 16.0f - 0.5f;
        const float fx = floorf(ix), fy = floorf(iy), fz = floorf(iz);
        const float wx = ix - fx, wy = iy - fy, wz = iz - fz;
        const int x0 = (int)fminf(fmaxf(fx, 0.0f), 31.0f);
        const int x1 = (int)fminf(fmaxf(fx + 1.0f, 0.0f), 31.0f);
        const int y0 = (int)fminf(fmaxf(fy, 0.0f), 31.0f);
        const int y1 = (int)fminf(fmaxf(fy + 1.0f, 0.0f), 31.0f);
        const int z0 = (int)fminf(fmaxf(fz, 0.0f), 31.0f);
        const int z1 = (int)fminf(fmaxf(fz + 1.0f, 0.0f), 31.0f);
        const int i000 = (z0 * 32 + y0) * 32 + x0, i001 = (z0 * 32 + y0) * 32 + x1;
        const int i010 = (z0 * 32 + y1) * 32 + x0, i011 = (z0 * 32 + y1) * 32 + x1;
        const int i100 = (z1 * 32 + y0) * 32 + x0, i101 = (z1 * 32 + y0) * 32 + x1;
        const int i110 = (z1 * 32 + y1) * 32 + x0, i111 = (z1 * 32 + y1) * 32 + x1;
        const float omx = 1.0f - wx, omy = 1.0f - wy, omz = 1.0f - wz;
        const float w000 = omz * omy * omx, w001 = omz * omy * wx;
        const float w010 = omz * wy * omx,  w011 = omz * wy * wx;
        const float w100 = wz * omy * omx,  w101 = wz * omy * wx;
        const float w110 = wz * wy * omx,   w111 = wz * wy * wx;

        f32x4 a;
        if (use_cl) {
            const float* vb = volcl + (size_t)bi * 32768 * 32 + g * 4;
            a  = w000 * *(const f32x4*)(vb + (size_t)i000 * 32);
            a += w001 * *(const f32x4*)(vb + (size_t)i001 * 32);
            a += w010 * *(const f32x4*)(vb + (size_t)i010 * 32);
            a += w011 * *(const f32x4*)(vb + (size_t)i011 * 32);
            a += w100 * *(const f32x4*)(vb + (size_t)i100 * 32);
            a += w101 * *(const f32x4*)(vb + (size_t)i101 * 32);
            a += w110 * *(const f32x4*)(vb + (size_t)i110 * 32);
            a += w111 * *(const f32x4*)(vb + (size_t)i111 * 32);
        } else {
            const float* vb = vol + ((size_t)bi * 32 + (size_t)g * 4) * 32768;
#pragma unroll
            for (int c = 0; c < 4; ++c) {
                const float* vc = vb + (size_t)c * 32768;
                a[c] = vc[i000] * w000 + vc[i001] * w001 + vc[i010] * w010 + vc[i011] * w011 +
                       vc[i100] * w100 + vc[i101] * w101 + vc[i110] * w110 + vc[i111] * w111;
            }
        }
        ushort4 sv;
        sv.x = f2bf(a[0]); sv.y = f2bf(a[1]); sv.z = f2bf(a[2]); sv.w = f2bf(a[3]);
        *(ushort4*)(S + p * 40 + g * 4) = sv;
    }
    __syncthreads();

    dense_sin_layer<32, 40>(S, A0, Wb + W0_OFF, b0, g, lr, lc);
    __syncthreads();
    dense_sin_layer<256, 264>(A0, A1, Wb + W1_OFF, b1, g, lr, lc);
    __syncthreads();
    dense_sin_layer<256, 264>(A1, A0, Wb + W2_OFF, b2, g, lr, lc);
    __syncthreads();
    dense_sin_layer<256, 264>(A0, A1, Wb + W3_OFF, b3, g, lr, lc);
    __syncthreads();

    // ---- final 256 -> 4 (waves 0..3, p-tile = wave) ----
    if (g < 4) {
        f32x4 acc = {0.0f, 0.0f, 0.0f, 0.0f};
        const ushort* Wfb = Wb + WF_OFF;
        const int wr = lr < 4 ? lr : 3;   // rows >=4 produce unused garbage
#pragma unroll
        for (int ks = 0; ks < 8; ++ks) {
            const int kb = ks * 32 + lc * 8;
            const bf16x8 wf = *(const bf16x8*)(Wfb + wr * 256 + kb);
            const bf16x8 af = *(const bf16x8*)(A1 + (g * 16 + lr) * 264 + kb);
            acc = __builtin_amdgcn_mfma_f32_16x16x32_bf16(wf, af, acc, 0, 0, 0);
        }
        if (lc == 0) {
            const long long oi = base + g * 16 + lr;
            if (oi < total) {
                float4 o;
                o.x = fast_sigmoid(acc[0] + bfin[0]);
                o.y = fast_sigmoid(acc[1] + bfin[1]);
                o.z = fast_sigmoid(acc[2] + bfin[2]);
                o.w = acc[3] + bfin[3];
                *(float4*)(out + oi * 4) = o;
            }
        }
    }
}

extern "C" void kernel_launch(void* const* d_in, const int* in_sizes, int n_in,
                              void* d_out, int out_size, void* d_ws, size_t ws_size,
                              hipStream_t stream) {
    const float* points = (const float*)d_in[0];
    const float* vol    = (const float*)d_in[1];
    const float* W0 = (const float*)d_in[2];
    const float* b0 = (const float*)d_in[3];
    const float* W1 = (const float*)d_in[4];
    const float* b1 = (const float*)d_in[5];
    const float* W2 = (const float*)d_in[6];
    const float* b2 = (const float*)d_in[7];
    const float* W3 = (const float*)d_in[8];
    const float* b3 = (const float*)d_in[9];
    const float* Wf = (const float*)d_in[10];
    const float* bf = (const float*)d_in[11];

    const int B = in_sizes[1] / (32 * 32 * 32 * 32);
    const int N = in_sizes[0] / (3 * B);
    const long long total = (long long)B * N;
    const int tiles = (int)((total + 63) / 64);

    ushort* Wb = (ushort*)d_ws;
    // weight conversion (every call; deterministic)
    cvt_bf16<<<(8192 + 255) / 256, 256, 0, stream>>>(W0, Wb + W0_OFF, 8192);
    cvt_bf16<<<(65536 + 255) / 256, 256, 0, stream>>>(W1, Wb + W1_OFF, 65536);
    cvt_bf16<<<(65536 + 255) / 256, 256, 0, stream>>>(W2, Wb + W2_OFF, 65536);
    cvt_bf16<<<(65536 + 255) / 256, 256, 0, stream>>>(W3, Wb + W3_OFF, 65536);
    cvt_bf16<<<(1024 + 255) / 256, 256, 0, stream>>>(Wf, Wb + WF_OFF, 1024);

    const int use_cl = (ws_size >= (size_t)WTS_BYTES + (size_t)B * 32768 * 32 * 4) ? 1 : 0;
    float* volcl = (float*)((char*)d_ws + WTS_BYTES);
    if (use_cl) {
        const int nvox = B * 32768;
        vol_chlast<<<(nvox + 255) / 256, 256, 0, stream>>>(vol, volcl, nvox);
    }

    const size_t shmem = (size_t)(2560 + 2 * 16896) * sizeof(ushort);  // 72704 B
    hipFuncSetAttribute((const void*)siren_mfma,
                        hipFuncAttributeMaxDynamicSharedMemorySize, (int)shmem);

    siren_mfma<<<tiles, THREADS, shmem, stream>>>(
        points, vol, b0, b1, b2, b3, bf, Wb, volcl, use_cl,
        (float*)d_out, total, N);
}

// Round 3
// 203.806 us; speedup vs baseline: 20.6411x; 1.0214x over previous
//
#include <hip/hip_runtime.h>
#include <math.h>

#define THREADS 256

typedef __attribute__((ext_vector_type(8))) short bf16x8;
typedef __attribute__((ext_vector_type(4))) float f32x4;

// ws layout (bf16 elem offsets for weights; then f32 channel-last volume)
#define W0_OFF 0        // 256*32
#define W1_OFF 8192     // 256*256
#define W2_OFF 73728
#define W3_OFF 139264
#define WF_OFF 204800   // 4*256
#define WTS_BYTES 411648            // 205824 * 2, 16B-aligned

__device__ __forceinline__ ushort f2bf(float f) {
    union { float f; unsigned u; } v; v.f = f;
    unsigned r = v.u + 0x7FFFu + ((v.u >> 16) & 1u);
    return (ushort)(r >> 16);
}

__device__ __forceinline__ float fast_sigmoid(float x) {
    return 1.0f / (1.0f + __expf(-x));
}

// XOR-swizzled element offset into a [64][256] ushort buffer (512B rows).
// 16B chunks within a row are XOR'd with row&7 -> 16 lanes reading 16
// different rows at the same col hit 8 distinct chunk slots (2-way = free).
__device__ __forceinline__ int swz(int row, int col) {
    const int chunk = (col >> 3) ^ (row & 7);
    return row * 256 + chunk * 8 + (col & 7);
}

// ---------------- prep kernels ----------------
__global__ void cvt_bf16(const float* __restrict__ src, ushort* __restrict__ dst, int n) {
    int i = blockIdx.x * 256 + threadIdx.x;
    if (i < n) dst[i] = f2bf(src[i]);
}

// vol [B][32][32768] f32 -> dst [B*32768][32] f32 (channel-last)
__global__ void vol_chlast(const float* __restrict__ vol, float* __restrict__ dst, int nvox) {
    int v = blockIdx.x * 256 + threadIdx.x;
    if (v >= nvox) return;
    const int b = v >> 15, idx = v & 32767;
    const float* s = vol + (size_t)b * 32 * 32768 + idx;
    float* d = dst + (size_t)v * 32;
#pragma unroll
    for (int c = 0; c < 32; ++c) d[c] = s[(size_t)c * 32768];
}

// ---------------- main fused kernel ----------------
// LDS (ushort): S[64][40]=2560, A0[64][256]=16384, A1[64][256]=16384
// total = 35328 ushort = 70656 B  -> 2 blocks/CU
extern __shared__ ushort ldsu[];

// One dense layer + sin. Wave covers ALL 64 points x 64 neurons (nbase..+63).
// acc[ptt][nt]: ptt = 16-point tile, nt = 16-neuron tile. 16 indep MFMA chains.
template <int K, bool ISWZ>
__device__ __forceinline__ void dense_sin_layer(const ushort* __restrict__ in,
                                                ushort* __restrict__ outb,
                                                const ushort* __restrict__ Wl,
                                                const float* __restrict__ bias,
                                                int nbase, int lr, int lc) {
    f32x4 acc[4][4];
#pragma unroll
    for (int nt = 0; nt < 4; ++nt) {
        const f32x4 bv = *(const f32x4*)(bias + nbase + nt * 16 + lc * 4);
#pragma unroll
        for (int ptt = 0; ptt < 4; ++ptt) acc[ptt][nt] = bv;
    }

#pragma unroll
    for (int ks = 0; ks < K / 32; ++ks) {
        const int kb = ks * 32 + lc * 8;
        bf16x8 wf[4];
#pragma unroll
        for (int nt = 0; nt < 4; ++nt)
            wf[nt] = *(const bf16x8*)(Wl + (size_t)(nbase + nt * 16 + lr) * K + kb);
#pragma unroll
        for (int ptt = 0; ptt < 4; ++ptt) {
            const int row = ptt * 16 + lr;
            const bf16x8 af = *(const bf16x8*)(in + (ISWZ ? swz(row, kb) : row * 40 + kb));
#pragma unroll
            for (int nt = 0; nt < 4; ++nt)
                acc[ptt][nt] = __builtin_amdgcn_mfma_f32_16x16x32_bf16(wf[nt], af, acc[ptt][nt], 0, 0, 0);
        }
    }

    // epilogue: sin -> bf16; lane holds 4 consecutive neurons for point row
#pragma unroll
    for (int ptt = 0; ptt < 4; ++ptt) {
        const int row = ptt * 16 + lr;
#pragma unroll
        for (int nt = 0; nt < 4; ++nt) {
            const int n0 = nbase + nt * 16 + lc * 4;
            ushort4 o;
            o.x = f2bf(__sinf(acc[ptt][nt][0]));
            o.y = f2bf(__sinf(acc[ptt][nt][1]));
            o.z = f2bf(__sinf(acc[ptt][nt][2]));
            o.w = f2bf(__sinf(acc[ptt][nt][3]));
            *(ushort4*)(outb + swz(row, n0)) = o;
        }
    }
}

__global__ __launch_bounds__(THREADS, 2)
void siren_mfma(const float* __restrict__ points,
                const float* __restrict__ vol,
                const float* __restrict__ b0, const float* __restrict__ b1,
                const float* __restrict__ b2, const float* __restrict__ b3,
                const float* __restrict__ bfin,
                const ushort* __restrict__ Wb,
                const float* __restrict__ volcl, int use_cl,
                float* __restrict__ out, long long total, int N) {
    ushort* S  = ldsu;            // [64][40]
    ushort* A0 = ldsu + 2560;     // [64][256] swizzled
    ushort* A1 = A0 + 16384;

    const int tid = (int)threadIdx.x;
    const int w = tid >> 6;       // wave id (0..3) -> neuron group
    const int lane = tid & 63;
    const int lr = lane & 15;
    const int lc = lane >> 4;

    const long long base = (long long)blockIdx.x * 64;

    // ---- trilinear border sample: thread -> point tid&63, channels (tid>>6)*8..+7
    {
        const int p = tid & 63;
        const int cg = tid >> 6;  // 0..3, 8 channels each
        const long long gidx = base + p;
        const long long gp = gidx < total ? gidx : total - 1;
        const int bi = (int)(gp / N);
        const float* pp = points + gp * 3;
        const float sc = 1.0f / 0.6f;
        const float ix = (pp[0] * sc + 1.0f) * 16.0f - 0.5f;
        const float iy = (pp[1] * sc + 1.0f) * 16.0f - 0.5f;
        const float iz = (pp[2] * sc + 1.0f) * 16.0f - 0.5f;
        const float fx = floorf(ix), fy = floorf(iy), fz = floorf(iz);
        const float wx = ix - fx, wy = iy - fy, wz = iz - fz;
        const int x0 = (int)fminf(fmaxf(fx, 0.0f), 31.0f);
        const int x1 = (int)fminf(fmaxf(fx + 1.0f, 0.0f), 31.0f);
        const int y0 = (int)fminf(fmaxf(fy, 0.0f), 31.0f);
        const int y1 = (int)fminf(fmaxf(fy + 1.0f, 0.0f), 31.0f);
        const int z0 = (int)fminf(fmaxf(fz, 0.0f), 31.0f);
        const int z1 = (int)fminf(fmaxf(fz + 1.0f, 0.0f), 31.0f);
        const int i000 = (z0 * 32 + y0) * 32 + x0, i001 = (z0 * 32 + y0) * 32 + x1;
        const int i010 = (z0 * 32 + y1) * 32 + x0, i011 = (z0 * 32 + y1) * 32 + x1;
        const int i100 = (z1 * 32 + y0) * 32 + x0, i101 = (z1 * 32 + y0) * 32 + x1;
        const int i110 = (z1 * 32 + y1) * 32 + x0, i111 = (z1 * 32 + y1) * 32 + x1;
        const float omx = 1.0f - wx, omy = 1.0f - wy, omz = 1.0f - wz;
        const float w000 = omz * omy * omx, w001 = omz * omy * wx;
        const float w010 = omz * wy * omx,  w011 = omz * wy * wx;
        const float w100 = wz * omy * omx,  w101 = wz * omy * wx;
        const float w110 = wz * wy * omx,   w111 = wz * wy * wx;

        f32x4 a[2];
        if (use_cl) {
            const float* vb = volcl + (size_t)bi * 32768 * 32 + cg * 8;
#pragma unroll
            for (int h = 0; h < 2; ++h) {
                const float* vh = vb + h * 4;
                a[h]  = w000 * *(const f32x4*)(vh + (size_t)i000 * 32);
                a[h] += w001 * *(const f32x4*)(vh + (size_t)i001 * 32);
                a[h] += w010 * *(const f32x4*)(vh + (size_t)i010 * 32);
                a[h] += w011 * *(const f32x4*)(vh + (size_t)i011 * 32);
                a[h] += w100 * *(const f32x4*)(vh + (size_t)i100 * 32);
                a[h] += w101 * *(const f32x4*)(vh + (size_t)i101 * 32);
                a[h] += w110 * *(const f32x4*)(vh + (size_t)i110 * 32);
                a[h] += w111 * *(const f32x4*)(vh + (size_t)i111 * 32);
            }
        } else {
            const float* vb = vol + ((size_t)bi * 32 + (size_t)cg * 8) * 32768;
#pragma unroll
            for (int c = 0; c < 8; ++c) {
                const float* vc = vb + (size_t)c * 32768;
                a[c >> 2][c & 3] =
                    vc[i000] * w000 + vc[i001] * w001 + vc[i010] * w010 + vc[i011] * w011 +
                    vc[i100] * w100 + vc[i101] * w101 + vc[i110] * w110 + vc[i111] * w111;
            }
        }
#pragma unroll
        for (int h = 0; h < 2; ++h) {
            ushort4 sv;
            sv.x = f2bf(a[h][0]); sv.y = f2bf(a[h][1]);
            sv.z = f2bf(a[h][2]); sv.w = f2bf(a[h][3]);
            *(ushort4*)(S + p * 40 + cg * 8 + h * 4) = sv;
        }
    }
    __syncthreads();

    const int nbase = w * 64;
    dense_sin_layer<32,  false>(S,  A0, Wb + W0_OFF, b0, nbase, lr, lc);
    __syncthreads();
    dense_sin_layer<256, true >(A0, A1, Wb + W1_OFF, b1, nbase, lr, lc);
    __syncthreads();
    dense_sin_layer<256, true >(A1, A0, Wb + W2_OFF, b2, nbase, lr, lc);
    __syncthreads();
    dense_sin_layer<256, true >(A0, A1, Wb + W3_OFF, b3, nbase, lr, lc);
    __syncthreads();

    // ---- final 256 -> 4: wave w covers points w*16..w*16+15 ----
    {
        f32x4 acc = {0.0f, 0.0f, 0.0f, 0.0f};
        const ushort* Wfb = Wb + WF_OFF;
        const int wr = lr < 4 ? lr : 3;   // rows >=4 produce unused garbage
#pragma unroll
        for (int ks = 0; ks < 8; ++ks) {
            const int kb = ks * 32 + lc * 8;
            const bf16x8 wf = *(const bf16x8*)(Wfb + wr * 256 + kb);
            const bf16x8 af = *(const bf16x8*)(A1 + swz(w * 16 + lr, kb));
            acc = __builtin_amdgcn_mfma_f32_16x16x32_bf16(wf, af, acc, 0, 0, 0);
        }
        if (lc == 0) {
            const long long oi = base + w * 16 + lr;
            if (oi < total) {
                float4 o;
                o.x = fast_sigmoid(acc[0] + bfin[0]);
                o.y = fast_sigmoid(acc[1] + bfin[1]);
                o.z = fast_sigmoid(acc[2] + bfin[2]);
                o.w = acc[3] + bfin[3];
                *(float4*)(out + oi * 4) = o;
            }
        }
    }
}

extern "C" void kernel_launch(void* const* d_in, const int* in_sizes, int n_in,
                              void* d_out, int out_size, void* d_ws, size_t ws_size,
                              hipStream_t stream) {
    const float* points = (const float*)d_in[0];
    const float* vol    = (const float*)d_in[1];
    const float* W0 = (const float*)d_in[2];
    const float* b0 = (const float*)d_in[3];
    const float* W1 = (const float*)d_in[4];
    const float* b1 = (const float*)d_in[5];
    const float* W2 = (const float*)d_in[6];
    const float* b2 = (const float*)d_in[7];
    const float* W3 = (const float*)d_in[8];
    const float* b3 = (const float*)d_in[9];
    const float* Wf = (const float*)d_in[10];
    const float* bf = (const float*)d_in[11];

    const int B = in_sizes[1] / (32 * 32 * 32 * 32);
    const int N = in_sizes[0] / (3 * B);
    const long long total = (long long)B * N;
    const int tiles = (int)((total + 63) / 64);

    ushort* Wb = (ushort*)d_ws;
    cvt_bf16<<<(8192 + 255) / 256, 256, 0, stream>>>(W0, Wb + W0_OFF, 8192);
    cvt_bf16<<<(65536 + 255) / 256, 256, 0, stream>>>(W1, Wb + W1_OFF, 65536);
    cvt_bf16<<<(65536 + 255) / 256, 256, 0, stream>>>(W2, Wb + W2_OFF, 65536);
    cvt_bf16<<<(65536 + 255) / 256, 256, 0, stream>>>(W3, Wb + W3_OFF, 65536);
    cvt_bf16<<<(1024 + 255) / 256, 256, 0, stream>>>(Wf, Wb + WF_OFF, 1024);

    const int use_cl = (ws_size >= (size_t)WTS_BYTES + (size_t)B * 32768 * 32 * 4) ? 1 : 0;
    float* volcl = (float*)((char*)d_ws + WTS_BYTES);
    if (use_cl) {
        const int nvox = B * 32768;
        vol_chlast<<<(nvox + 255) / 256, 256, 0, stream>>>(vol, volcl, nvox);
    }

    const size_t shmem = (size_t)(2560 + 2 * 16384) * sizeof(ushort);  // 70656 B
    hipFuncSetAttribute((const void*)siren_mfma,
                        hipFuncAttributeMaxDynamicSharedMemorySize, (int)shmem);

    siren_mfma<<<tiles, THREADS, shmem, stream>>>(
        points, vol, b0, b1, b2, b3, bf, Wb, volcl, use_cl,
        (float*)d_out, total, N);
}